// Round 13
// baseline (177.228 us; speedup 1.0000x reference)
//
#include <hip/hip_runtime.h>
#include <math.h>

#define NB 4096
#define ND 512
#define K2 1024
#define NT8 8  // K2 / 128 K-tiles

typedef __attribute__((ext_vector_type(16))) float f32x16;

// ---------------------------------------------------------------------------
// Kernel 1: build A=[v_mean|v_sigma] (4096x1024 fp8 e4m3) and B likewise, in
// MFMA FRAGMENT ORDER (verified R10-R12):
//   A: [rb(32)][t(8)][g(4)][ks8(8)][lane(64)=kh*32+r5][8B]   (131072 B / rb)
//   B: [rb(16)][t(8)][g(8)][ks8(8)][lane(64)][8B]            (262144 B / rb)
// element (row,k): g=(row>>5)&3 (A) or &7 (B), r5=row&31; t=k>>7,
// ks8=(k>>4)&7, kh=(k>>3)&1, j=k&7.
// Row norms a_sq[i]=Σmean²+Σvar via atomicAdd (arrays zeroed by memset).
// Block 0 also zero-inits out[0] (combine accumulates into it atomically).
// ---------------------------------------------------------------------------
__global__ __launch_bounds__(256) void prep_kernel(
    const float* __restrict__ v_mean, const float* __restrict__ v_var,
    const float* __restrict__ t_mean, const float* __restrict__ t_var,
    unsigned char* __restrict__ Afp, unsigned char* __restrict__ Bfp,
    float* __restrict__ a_sq, float* __restrict__ b_sq,
    float* __restrict__ out) {
  __shared__ __align__(8) unsigned char lfp[32 * 132];  // 132B row stride
  int bid = blockIdx.x;
  int tid = threadIdx.x;
  if (bid == 0 && tid == 0) out[0] = 0.f;
  const float* src;
  unsigned char* dst;
  float* sq;
  int row0;
  bool isVar;
  if (bid < 1024) {
    int rb = bid >> 5, t = (bid >> 2) & 7, g = bid & 3;
    row0 = rb * 128 + g * 32;
    isVar = t >= 4;
    src = (isVar ? v_var : v_mean) + (size_t)row0 * ND + (t & 3) * 128;
    dst = Afp + (size_t)rb * 131072 + t * 16384 + g * 4096;
    sq = a_sq;
  } else {
    int b = bid - 1024;
    int rb = b >> 6, t = (b >> 3) & 7, g = b & 7;
    row0 = rb * 256 + g * 32;
    isVar = t >= 4;
    src = (isVar ? t_var : t_mean) + (size_t)row0 * ND + (t & 3) * 128;
    dst = Bfp + (size_t)rb * 262144 + t * 32768 + g * 4096;
    sq = b_sq;
  }
  // Phase 1: coalesced read 32x128 f32, fp8->LDS, per-row norm partial.
#pragma unroll
  for (int q = 0; q < 4; ++q) {
    int flat = q * 256 + tid;
    int row = flat >> 5, col4 = flat & 31;
    float4 v = *(const float4*)(src + row * ND + col4 * 4);
    float p;
    float4 w;
    if (isVar) {
      p = (v.x + v.y) + (v.z + v.w);
      w.x = sqrtf(v.x); w.y = sqrtf(v.y); w.z = sqrtf(v.z); w.w = sqrtf(v.w);
    } else {
      p = (v.x * v.x + v.y * v.y) + (v.z * v.z + v.w * v.w);
      w = v;
    }
    int p01 = __builtin_amdgcn_cvt_pk_fp8_f32(w.x, w.y, 0, false);
    int p23 = __builtin_amdgcn_cvt_pk_fp8_f32(w.z, w.w, 0, false);
    unsigned u = (unsigned)(p01 & 0xFFFF) | ((unsigned)(p23 & 0xFFFF) << 16);
    *(unsigned*)(lfp + row * 132 + col4 * 4) = u;
#pragma unroll
    for (int o = 1; o <= 16; o <<= 1) p += __shfl_xor(p, o);
    if ((tid & 31) == 0) atomicAdd(sq + row0 + row, p);
  }
  __syncthreads();
  // Phase 2: fragment-order writes (coalesced 512B per wave-instruction).
  {
    int wv = tid >> 6, l = tid & 63;
    int r5 = l & 31, kh = l >> 5;
#pragma unroll
    for (int cc = 0; cc < 2; ++cc) {
      int ks8 = wv * 2 + cc;
      unsigned long long d =
          *(const unsigned long long*)(lfp + r5 * 132 + ks8 * 16 + kh * 8);
      *(unsigned long long*)(dst + ks8 * 512 + l * 8) = d;
    }
  }
}

// ---------------------------------------------------------------------------
// Kernel 2: 128x256-tile fp8 GEMM via mfma_f32_32x32x16_fp8_fp8, BK=128,
// SINGLE-buffered LDS (48 KB -> 2 blocks/CU TLP), *** 4 waves *** (2x2),
// wave = 64x128 (2mi x 4ni of 32x32): per kstep 6 conflict-free b64 reads
// feed 8 MFMA (ratio 1.33 vs R11's 1.0), 64 MFMA per wave per barrier
// interval (2x R11), 8 independent acc chains for ILP.
// acc = 2x4 f32x16 = 128 AGPRs; arch VGPR ~50 -> no spill at (256,2).
// Fragment-ordered operands: staging = linear 16B chunks; frag read =
// g*4096 + ks*512 + lane*8 (lane-linear, conflict-free — verified R11/R12).
// Fused online-LSE partials in the epilogue:
//   rowM/rowS[row][64]  ch = bn*4+wc*2+c     (c = ni-pair, 64-col chunks)
//   colM/colS[col][64]  ch = bm*2+wr
// ---------------------------------------------------------------------------
__global__ __launch_bounds__(256, 2) void gemm_fused_kernel(
    const unsigned char* __restrict__ Afp, const unsigned char* __restrict__ Bfp,
    const float* __restrict__ a_sq, const float* __restrict__ b_sq,
    const float* __restrict__ log_temp,
    float* __restrict__ rowM, float* __restrict__ rowS,
    float* __restrict__ colM, float* __restrict__ colS,
    float* __restrict__ diag) {
  __shared__ unsigned char ldsA[16384];  // [g(4)][ks8(8)][lane][8B]
  __shared__ unsigned char ldsB[32768];  // [g(8)][ks8(8)][lane][8B]
  int bid = blockIdx.x;
  // XCD-aware swizzle: 512 blocks, 8 XCDs -> 64 contiguous per XCD (bijective).
  int swz = (bid & 7) * 64 + (bid >> 3);
  int bm = swz >> 4, bn = swz & 15;  // 32 x 16 grid
  int brow = bm * 128, bcol = bn * 256;
  int tid = threadIdx.x;
  int lane = tid & 63, wid = tid >> 6;
  int wr = wid >> 1, wc = wid & 1;  // 2x2 wave grid, wave = 64x128
  int l31 = lane & 31, kh = lane >> 5;

  const unsigned char* Ablk = Afp + (size_t)bm * 131072;
  const unsigned char* Bblk = Bfp + (size_t)bn * 262144;
  unsigned off16 = (unsigned)tid * 16;

  // Staging: 12 x 16B loads/thread per tile (A 16KB: 4, B 32KB: 8). Linear.
#define STAGE(TT)                                                              \
  {                                                                            \
    _Pragma("unroll") for (int s = 0; s < 4; ++s)                              \
        __builtin_amdgcn_global_load_lds(                                      \
            (const __attribute__((address_space(1))) unsigned int*)(Ablk +     \
                (unsigned)(TT) * 16384u + s * 4096u + off16),                  \
            (__attribute__((address_space(3))) unsigned int*)(ldsA +           \
                s * 4096u + off16),                                            \
            16, 0, 0);                                                         \
    _Pragma("unroll") for (int s = 0; s < 8; ++s)                              \
        __builtin_amdgcn_global_load_lds(                                      \
            (const __attribute__((address_space(1))) unsigned int*)(Bblk +     \
                (unsigned)(TT) * 32768u + s * 4096u + off16),                  \
            (__attribute__((address_space(3))) unsigned int*)(ldsB +           \
                s * 4096u + off16),                                            \
            16, 0, 0);                                                         \
  }

  // Fragment bases (byte offsets): lane-linear, conflict-free.
  unsigned aB0 = (unsigned)(wr * 2 + 0) * 4096 + lane * 8;
  unsigned aB1 = (unsigned)(wr * 2 + 1) * 4096 + lane * 8;
  unsigned bBs = (unsigned)(wc * 4) * 4096 + lane * 8;  // +ni*4096

  f32x16 acc[2][4] = {};

  STAGE(0);
  asm volatile("s_waitcnt vmcnt(0)" ::: "memory");
  __builtin_amdgcn_s_barrier();

  for (int tt = 0; tt < NT8; ++tt) {
    long a0, a1, b0, b1, b2, b3;
#define LOADKS(KO)                                                             \
    a0 = *(const long*)(ldsA + aB0 + (KO));                                    \
    a1 = *(const long*)(ldsA + aB1 + (KO));                                    \
    b0 = *(const long*)(ldsB + bBs + 0 * 4096 + (KO));                         \
    b1 = *(const long*)(ldsB + bBs + 1 * 4096 + (KO));                         \
    b2 = *(const long*)(ldsB + bBs + 2 * 4096 + (KO));                         \
    b3 = *(const long*)(ldsB + bBs + 3 * 4096 + (KO));
#define MFMA8()                                                                \
    __builtin_amdgcn_s_setprio(1);                                             \
    acc[0][0] = __builtin_amdgcn_mfma_f32_32x32x16_fp8_fp8(a0, b0, acc[0][0], 0, 0, 0); \
    acc[0][1] = __builtin_amdgcn_mfma_f32_32x32x16_fp8_fp8(a0, b1, acc[0][1], 0, 0, 0); \
    acc[0][2] = __builtin_amdgcn_mfma_f32_32x32x16_fp8_fp8(a0, b2, acc[0][2], 0, 0, 0); \
    acc[0][3] = __builtin_amdgcn_mfma_f32_32x32x16_fp8_fp8(a0, b3, acc[0][3], 0, 0, 0); \
    acc[1][0] = __builtin_amdgcn_mfma_f32_32x32x16_fp8_fp8(a1, b0, acc[1][0], 0, 0, 0); \
    acc[1][1] = __builtin_amdgcn_mfma_f32_32x32x16_fp8_fp8(a1, b1, acc[1][1], 0, 0, 0); \
    acc[1][2] = __builtin_amdgcn_mfma_f32_32x32x16_fp8_fp8(a1, b2, acc[1][2], 0, 0, 0); \
    acc[1][3] = __builtin_amdgcn_mfma_f32_32x32x16_fp8_fp8(a1, b3, acc[1][3], 0, 0, 0); \
    __builtin_amdgcn_s_setprio(0);
    // ksteps 0..6
#pragma unroll
    for (int ks = 0; ks < 7; ++ks) {
      LOADKS((unsigned)ks * 512)
      MFMA8()
    }
    // kstep 7: read, drain own LDS reads, barrier -> tile fully consumed.
    LOADKS(3584u)
    asm volatile("s_waitcnt lgkmcnt(0)" ::: "memory");
    __builtin_amdgcn_s_barrier();
    if (tt + 1 < NT8) STAGE(tt + 1);
    MFMA8()
    asm volatile("s_waitcnt vmcnt(0)" ::: "memory");
    __builtin_amdgcn_s_barrier();
  }

  // ---- epilogue: logits in-place, diag, fused online-LSE partials ----
  // 32x32 C/D layout (m74/m101): col=lane&31, row=(reg&3)+8*(reg>>2)+4*kh.
  float temp = fminf(expf(log_temp[0]), 100.0f);
#pragma unroll
  for (int mi = 0; mi < 2; ++mi) {
#pragma unroll
    for (int reg = 0; reg < 16; ++reg) {
      int rl = wr * 64 + mi * 32 + (reg & 3) + 8 * (reg >> 2) + 4 * kh;
      float asq = a_sq[brow + rl];
#pragma unroll
      for (int ni = 0; ni < 4; ++ni) {
        float bsq = b_sq[bcol + wc * 128 + ni * 32 + l31];
        acc[mi][ni][reg] = -temp * (asq + bsq - 2.0f * acc[mi][ni][reg]);
      }
    }
  }
  // Diagonal: block contains global diag iff (bm>>1)==bn.
  if ((bm >> 1) == bn) {
#pragma unroll
    for (int mi = 0; mi < 2; ++mi)
#pragma unroll
      for (int ni = 0; ni < 4; ++ni)
#pragma unroll
        for (int reg = 0; reg < 16; ++reg) {
          int rl = wr * 64 + mi * 32 + (reg & 3) + 8 * (reg >> 2) + 4 * kh;
          int cl = wc * 128 + ni * 32 + l31;
          if (brow + rl == bcol + cl) diag[brow + rl] = acc[mi][ni][reg];
        }
  }
  // Row partials: per (mi,reg) x 2 ni-pairs: 2 in-lane + 32-col reduce (l31).
#pragma unroll
  for (int mi = 0; mi < 2; ++mi) {
#pragma unroll
    for (int reg = 0; reg < 16; ++reg) {
      int row = brow + wr * 64 + mi * 32 + (reg & 3) + 8 * (reg >> 2) + 4 * kh;
#pragma unroll
      for (int c = 0; c < 2; ++c) {
        float mx = fmaxf(acc[mi][2 * c][reg], acc[mi][2 * c + 1][reg]);
#pragma unroll
        for (int o = 1; o < 32; o <<= 1) mx = fmaxf(mx, __shfl_xor(mx, o));
        float s = __expf(acc[mi][2 * c][reg] - mx) + __expf(acc[mi][2 * c + 1][reg] - mx);
#pragma unroll
        for (int o = 1; o < 32; o <<= 1) s += __shfl_xor(s, o);
        if (l31 == 0) {
          int ch = bn * 4 + wc * 2 + c;
          rowM[(size_t)row * 64 + ch] = mx;
          rowS[(size_t)row * 64 + ch] = s;
        }
      }
    }
  }
  // Col partials: per ni: 32 in-lane (mi,reg) + merge kh halves (xor 32).
#pragma unroll
  for (int ni = 0; ni < 4; ++ni) {
    float mx = -INFINITY;
#pragma unroll
    for (int mi = 0; mi < 2; ++mi)
#pragma unroll
      for (int reg = 0; reg < 16; ++reg) mx = fmaxf(mx, acc[mi][ni][reg]);
    mx = fmaxf(mx, __shfl_xor(mx, 32));
    float s = 0.f;
#pragma unroll
    for (int mi = 0; mi < 2; ++mi)
#pragma unroll
      for (int reg = 0; reg < 16; ++reg) s += __expf(acc[mi][ni][reg] - mx);
    s += __shfl_xor(s, 32);
    if (kh == 0) {
      int col = bcol + wc * 128 + ni * 32 + l31;
      int ch = bm * 2 + wr;
      colM[(size_t)col * 64 + ch] = mx;
      colS[(size_t)col * 64 + ch] = s;
    }
  }
}

// ---------------------------------------------------------------------------
// Kernel 3: combine 64 chunk-partials per row/col -> (lse - diag), and
// atomically accumulate 0.5*mean into out (out zero-init'd by prep).
// ---------------------------------------------------------------------------
__global__ __launch_bounds__(256) void combine_kernel(
    const float* __restrict__ rowM, const float* __restrict__ rowS,
    const float* __restrict__ colM, const float* __restrict__ colS,
    const float* __restrict__ diag, float* __restrict__ out) {
  int b = blockIdx.x;
  int t = threadIdx.x;
  int wave = t >> 6, lane = t & 63;
  int isCol = b >> 10;
  int idx = (b & 1023) * 4 + wave;
  const float* PM = isCol ? colM : rowM;
  const float* PS = isCol ? colS : rowS;
  float M = PM[(size_t)idx * 64 + lane];
  float S = PS[(size_t)idx * 64 + lane];
#pragma unroll
  for (int o = 1; o < 64; o <<= 1) {
    float M2 = __shfl_xor(M, o), S2 = __shfl_xor(S, o);
    float nM = fmaxf(M, M2);
    S = S * __expf(M - nM) + S2 * __expf(M2 - nM);
    M = nM;
  }
  if (lane == 0) {
    float v = M + logf(S) - diag[idx];
    atomicAdd(out, v * (0.5f / (float)NB));
  }
}

extern "C" void kernel_launch(void* const* d_in, const int* in_sizes, int n_in,
                              void* d_out, int out_size, void* d_ws, size_t ws_size,
                              hipStream_t stream) {
  const float* v_mean = (const float*)d_in[0];
  const float* v_var = (const float*)d_in[1];
  const float* t_mean = (const float*)d_in[2];
  const float* t_var = (const float*)d_in[3];
  const float* log_temp = (const float*)d_in[4];
  float* out = (float*)d_out;

  char* ws = (char*)d_ws;
  unsigned char* Afp = (unsigned char*)ws;                       // 4 MiB
  unsigned char* Bfp = (unsigned char*)(ws + 4194304);           // 4 MiB
  float* rowM = (float*)(ws + 8388608);                          // 1 MiB each
  float* rowS = rowM + (size_t)NB * 64;
  float* colM = rowS + (size_t)NB * 64;
  float* colS = colM + (size_t)NB * 64;
  float* diag = colS + (size_t)NB * 64;                          // 16 KiB
  float* a_sq = diag + NB;
  float* b_sq = a_sq + NB;

  // Zero the atomic accumulators (a_sq, b_sq contiguous).
  hipMemsetAsync(a_sq, 0, 2 * (size_t)NB * sizeof(float), stream);
  prep_kernel<<<2048, 256, 0, stream>>>(v_mean, v_var, t_mean, t_var, Afp, Bfp,
                                        a_sq, b_sq, out);
  gemm_fused_kernel<<<512, 256, 0, stream>>>(Afp, Bfp, a_sq, b_sq, log_temp,
                                             rowM, rowS, colM, colS, diag);
  combine_kernel<<<2048, 256, 0, stream>>>(rowM, rowS, colM, colS, diag, out);
}